// Round 1
// baseline (465.548 us; speedup 1.0000x reference)
//
#include <hip/hip_runtime.h>
#include <hip/hip_bf16.h>
#include <cstdint>
#include <cstddef>

// Problem constants (reference: BATCH,SEQ,HIDDEN,N_TYPES = 8,1024,256,4; MAX_SPAN=12)
#define BATCH   8
#define SEQLEN  1024
#define HIDDEN  256
#define NTYPES  4
#define NSPAN   12222   // 1013*12 + (11+...+1)
#define NFULL   12156   // 1013*12 (spans with full 12-length runs)
#define NPAD    12288   // 96 tiles * 128 rows
#define KDIM    512     // 2*HIDDEN
#define NCOL    1024    // NTYPES*HIDDEN

typedef __bf16 bf16x8 __attribute__((ext_vector_type(8)));
typedef float  f32x4  __attribute__((ext_vector_type(4)));

#define AS1 __attribute__((address_space(1)))
#define AS3 __attribute__((address_space(3)))

__device__ __forceinline__ void load16(const __bf16* g, __bf16* l) {
    // 16B direct global->LDS; LDS dest must be wave-uniform base + lane*16 (it is:
    // each lane passes base + lane*8 elements). Global address is per-lane (gather OK).
    __builtin_amdgcn_global_load_lds((AS1 const void*)g, (AS3 void*)l, 16, 0, 0);
}

// ---- fp32 -> bf16 conversion (4 elems/thread) ----
__global__ void cvt_bf16(const float* __restrict__ src, __bf16* __restrict__ dst, int n) {
    int i = (blockIdx.x * 256 + threadIdx.x) * 4;
    if (i + 3 < n) {
        float4 f = *(const float4*)(src + i);
        struct alignas(8) B4 { __bf16 a, b, c, d; };
        B4 v;
        v.a = (__bf16)f.x; v.b = (__bf16)f.y; v.c = (__bf16)f.z; v.d = (__bf16)f.w;
        *(B4*)(dst + i) = v;
    }
}

// ---- span index tables, padded to NPAD with 0 (safe gather) ----
__global__ void mk_idx(int* __restrict__ sA, int* __restrict__ eA) {
    int n = blockIdx.x * 256 + threadIdx.x;
    if (n >= NPAD) return;
    int s = 0, e = 0;
    if (n < NFULL) {
        s = n / 12;
        e = s + (n - s * 12);
    } else if (n < NSPAN) {
        int r = n - NFULL;
        s = SEQLEN - 11;          // 1013, first tail start (11 spans)
        int cnt = 11;
        while (r >= cnt) { r -= cnt; --cnt; ++s; }
        e = s + r;
    }
    sA[n] = s; eA[n] = e;
}

// ---- main GEMM: C[b, n, j] = sum_k A[b,n,k] * Wbf[j][k] + bias[j] ----
// A gathered from Hbf rows via idxS/idxE.  128x128 tile, BK=32, 4 waves 2x2.
__global__ __launch_bounds__(256) void span_gemm(
    const __bf16* __restrict__ Hbf,   // [BATCH][SEQLEN][HIDDEN]
    const __bf16* __restrict__ Wbf,   // [NCOL][KDIM]  (n-major, k contiguous)
    const int*    __restrict__ idxS,
    const int*    __restrict__ idxE,
    const float*  __restrict__ bias,  // [NCOL]
    float*        __restrict__ out)   // [BATCH][NSPAN][NCOL]
{
    __shared__ alignas(16) __bf16 As[128 * 32];
    __shared__ alignas(16) __bf16 Bs[128 * 32];

    const int tid  = threadIdx.x;
    const int wave = tid >> 6;
    const int lane = tid & 63;
    const int wm   = (wave >> 1) * 64;   // wave row offset in tile
    const int wn   = (wave & 1) * 64;    // wave col offset in tile
    const int lr   = lane & 15;
    const int lq   = lane >> 4;

    const int j0 = blockIdx.x * 128;     // output column tile (8 tiles)
    const int n0 = blockIdx.y * 128;     // span-row tile (96 tiles)
    const int b  = blockIdx.z;           // batch

    // staging layout: linear bf16 index l -> row l>>5, col l&31 of the 128x32 tile.
    // Each thread stages two 16B chunks (wave covers 1024 elems contiguous).
    const int l0  = wave * 1024 + lane * 8;
    const int l1  = l0 + 512;
    const int mm0 = l0 >> 5, kk0 = l0 & 31;
    const int mm1 = l1 >> 5, kk1 = l1 & 31;

    const int s0 = idxS[n0 + mm0], e0 = idxE[n0 + mm0];
    const int s1 = idxS[n0 + mm1], e1 = idxE[n0 + mm1];

    const __bf16* hb = Hbf + (size_t)b * (SEQLEN * HIDDEN);
    const __bf16* w0 = Wbf + (size_t)(j0 + mm0) * KDIM + kk0;
    const __bf16* w1 = Wbf + (size_t)(j0 + mm1) * KDIM + kk1;

    f32x4 acc[4][4];
#pragma unroll
    for (int i = 0; i < 4; ++i)
#pragma unroll
        for (int j = 0; j < 4; ++j)
            acc[i][j] = (f32x4){0.f, 0.f, 0.f, 0.f};

    for (int half = 0; half < 2; ++half) {
        const __bf16* a0  = hb + (half ? e0 : s0) * HIDDEN + kk0;
        const __bf16* a1  = hb + (half ? e1 : s1) * HIDDEN + kk1;
        const __bf16* wb0 = w0 + half * HIDDEN;   // k advances by 256 per half
        const __bf16* wb1 = w1 + half * HIDDEN;

        for (int ks = 0; ks < 8; ++ks) {
            const int c0 = ks * 32;
            __syncthreads();              // previous compute done before overwrite
            load16(a0  + c0, &As[l0]);
            load16(a1  + c0, &As[l1]);
            load16(wb0 + c0, &Bs[l0]);
            load16(wb1 + c0, &Bs[l1]);
            __syncthreads();              // drains vmcnt, data visible

            bf16x8 af[4], bfv[4];
#pragma unroll
            for (int mi = 0; mi < 4; ++mi)
                af[mi] = *(const bf16x8*)(As + (wm + mi * 16 + lr) * 32 + lq * 8);
#pragma unroll
            for (int ni = 0; ni < 4; ++ni)
                bfv[ni] = *(const bf16x8*)(Bs + (wn + ni * 16 + lr) * 32 + lq * 8);
#pragma unroll
            for (int mi = 0; mi < 4; ++mi)
#pragma unroll
                for (int ni = 0; ni < 4; ++ni)
                    acc[mi][ni] = __builtin_amdgcn_mfma_f32_16x16x32_bf16(
                        af[mi], bfv[ni], acc[mi][ni], 0, 0, 0);
        }
    }

    // epilogue: +bias (depends only on column = lane lr within frag), masked store
    float bv[4];
#pragma unroll
    for (int ni = 0; ni < 4; ++ni) bv[ni] = bias[j0 + wn + ni * 16 + lr];

    const size_t obase = (size_t)b * NSPAN * NCOL;
#pragma unroll
    for (int mi = 0; mi < 4; ++mi) {
#pragma unroll
        for (int r = 0; r < 4; ++r) {
            const int n = n0 + wm + mi * 16 + lq * 4 + r;   // C/D: row = quad*4+reg
            if (n < NSPAN) {
                float* op = out + obase + (size_t)n * NCOL + (j0 + wn + lr);
#pragma unroll
                for (int ni = 0; ni < 4; ++ni)
                    op[ni * 16] = acc[mi][ni][r] + bv[ni];
            }
        }
    }
}

extern "C" void kernel_launch(void* const* d_in, const int* in_sizes, int n_in,
                              void* d_out, int out_size, void* d_ws, size_t ws_size,
                              hipStream_t stream) {
    const float* hid  = (const float*)d_in[0];   // [8,1024,256]
    const float* W    = (const float*)d_in[1];   // [4,256,512]
    const float* bias = (const float*)d_in[2];   // [4,256] -> flat [1024]
    float* out = (float*)d_out;

    // ws layout: Wbf (1 MB) | Hbf (4 MB) | idxS | idxE  (~5.34 MB total)
    char* ws = (char*)d_ws;
    __bf16* Wbf = (__bf16*)ws;
    __bf16* Hbf = (__bf16*)(ws + (size_t)1048576);
    int* idxS = (int*)(ws + (size_t)(1048576 + 4194304));
    int* idxE = idxS + NPAD;

    cvt_bf16<<<512,  256, 0, stream>>>(W,   Wbf, NCOL * KDIM);           // 524288
    cvt_bf16<<<2048, 256, 0, stream>>>(hid, Hbf, BATCH * SEQLEN * HIDDEN); // 2097152
    mk_idx<<<NPAD / 256, 256, 0, stream>>>(idxS, idxE);
    span_gemm<<<dim3(8, 96, BATCH), 256, 0, stream>>>(Hbf, Wbf, idxS, idxE, bias, out);
}